// Round 8
// baseline (526.130 us; speedup 1.0000x reference)
//
#include <hip/hip_runtime.h>

#define BB 512
#define TT 512
#define KK 64

typedef float v2f __attribute__((ext_vector_type(2)));

__device__ __forceinline__ float frl(float v, int lane) {
    return __int_as_float(__builtin_amdgcn_readlane(__float_as_int(v), lane));
}
__device__ __forceinline__ v2f vmax2(v2f a, v2f b) {
    v2f r; r.x = fmaxf(a.x, b.x); r.y = fmaxf(a.y, b.y); return r;
}
// wave-wide unsigned max; result valid in lane 63 (proven R4-R7)
__device__ __forceinline__ unsigned wave_umax63(unsigned x) {
    unsigned d;
    d = (unsigned)__builtin_amdgcn_update_dpp((int)x, (int)x, 0x111, 0xF, 0xF, false); x = x > d ? x : d;
    d = (unsigned)__builtin_amdgcn_update_dpp((int)x, (int)x, 0x112, 0xF, 0xF, false); x = x > d ? x : d;
    d = (unsigned)__builtin_amdgcn_update_dpp((int)x, (int)x, 0x114, 0xF, 0xF, false); x = x > d ? x : d;
    d = (unsigned)__builtin_amdgcn_update_dpp((int)x, (int)x, 0x118, 0xF, 0xF, false); x = x > d ? x : d;
    d = (unsigned)__builtin_amdgcn_update_dpp((int)x, (int)x, 0x142, 0xA, 0xF, false); x = x > d ? x : d;
    d = (unsigned)__builtin_amdgcn_update_dpp((int)x, (int)x, 0x143, 0xC, 0xF, false); x = x > d ? x : d;
    return x;
}

#define NEG_INF (-3.402823466e+38f)

// Two interleaved Viterbi steps (independent batches) via LDS broadcast.
// Batch B's DS reads + VALU fill batch A's chain stalls (1 wave/SIMD).
#define FSTEP2(PT0, PT1, TC0, TC1) do {                                         \
    la0[lane] = alpha0;                                                         \
    la1[lane] = alpha1;                                                         \
    asm volatile("" ::: "memory");                                              \
    v2f A0, A1, A2, A3, B0, B1, B2, B3;                                         \
    A0 = A1 = A2 = A3 = (v2f){NEG_INF, NEG_INF};                                \
    B0 = B1 = B2 = B3 = (v2f){NEG_INF, NEG_INF};                                \
    _Pragma("unroll")                                                           \
    for (int c = 0; c < 16; c += 2) {                                           \
        float4 xa = ((float4*)la0)[c];                                          \
        float4 xb = ((float4*)la1)[c];                                          \
        float4 ya = ((float4*)la0)[c + 1];                                      \
        float4 yb = ((float4*)la1)[c + 1];                                      \
        v2f lo, hi;                                                             \
        lo.x = xa.x; lo.y = xa.y; A0 = vmax2(A0, lo + tcl[c]);                  \
        hi.x = xa.z; hi.y = xa.w; A1 = vmax2(A1, hi + tch[c]);                  \
        lo.x = xb.x; lo.y = xb.y; B0 = vmax2(B0, lo + tcl[c]);                  \
        hi.x = xb.z; hi.y = xb.w; B1 = vmax2(B1, hi + tch[c]);                  \
        lo.x = ya.x; lo.y = ya.y; A2 = vmax2(A2, lo + tcl[c + 1]);              \
        hi.x = ya.z; hi.y = ya.w; A3 = vmax2(A3, hi + tch[c + 1]);              \
        lo.x = yb.x; lo.y = yb.y; B2 = vmax2(B2, lo + tcl[c + 1]);              \
        hi.x = yb.z; hi.y = yb.w; B3 = vmax2(B3, hi + tch[c + 1]);              \
    }                                                                           \
    v2f ma = vmax2(vmax2(A0, A1), vmax2(A2, A3));                               \
    v2f mb = vmax2(vmax2(B0, B1), vmax2(B2, B3));                               \
    float M0 = fmaxf(ma.x, ma.y);                                               \
    float M1 = fmaxf(mb.x, mb.y);                                               \
    alpha0 = (TC0) ? (PT0 + M0) : alpha0;                                       \
    alpha1 = (TC1) ? (PT1 + M1) : alpha1;                                       \
    *hp0 = alpha0; hp0 += KK;                                                   \
    *hp1 = alpha1; hp1 += KK;                                                   \
} while (0)

// ---------------------------------------------------------------------------
// Fused, 2 batches per wave: count -> max-only forward (alpha history to ws)
// -> interleaved DPP/ballot backtrace. 256 blocks x 1 wave (1 block/CU).
// ---------------------------------------------------------------------------
__global__ __launch_bounds__(64, 1) void crf_fused2(const float* __restrict__ pot,
                                                    const float* __restrict__ trans,
                                                    float* __restrict__ alphaH,
                                                    int* __restrict__ out) {
    __shared__ float tT[KK][KK + 1];   // tT[j][i] = trans[i][j] (backtrace)
    __shared__ float la0[KK], la1[KK]; // alpha broadcast buffers

    const int b0 = blockIdx.x * 2;
    const int b1 = b0 + 1;
    const int lane = threadIdx.x;
    const float* pb0 = pot + (size_t)b0 * TT * KK;
    const float* pb1 = pot + (size_t)b1 * TT * KK;
    float* hb0 = alphaH + (size_t)b0 * TT * KK;
    float* hb1 = alphaH + (size_t)b1 * TT * KK;
    int* ob0 = out + b0 * TT;
    int* ob1 = out + b1 * TT;

    // ---- seq_len per batch: count nonzeros (also warms L2 for pot) ----
    int cnt0 = 0, cnt1 = 0;
    {
        const float4* p40 = (const float4*)pb0;
        const float4* p41 = (const float4*)pb1;
        #pragma unroll 4
        for (int r = 0; r < 128; ++r) {
            float4 v = p40[lane + 64 * r];
            float4 u = p41[lane + 64 * r];
            cnt0 += (v.x != 0.f) + (v.y != 0.f) + (v.z != 0.f) + (v.w != 0.f);
            cnt1 += (u.x != 0.f) + (u.y != 0.f) + (u.z != 0.f) + (u.w != 0.f);
        }
        #pragma unroll
        for (int off = 32; off > 0; off >>= 1) {
            cnt0 += __shfl_xor(cnt0, off, 64);
            cnt1 += __shfl_xor(cnt1, off, 64);
        }
    }
    const int seqlen0 = cnt0 >> 6;
    const int seqlen1 = cnt1 >> 6;

    // ---- stage transposed trans for backtrace (same wave: no barrier) ----
    #pragma unroll 8
    for (int r = 0; r < KK; ++r) tT[lane][r] = trans[r * KK + lane];

    // ---- trans column 'lane' as v2f pairs; pin vs remat (proven R6) ----
    v2f tcl[16], tch[16];   // tcl[c] = rows 4c,4c+1; tch[c] = rows 4c+2,4c+3
    #pragma unroll
    for (int c = 0; c < 16; ++c) {
        v2f l2, h2;
        l2.x = trans[(4 * c + 0) * KK + lane]; l2.y = trans[(4 * c + 1) * KK + lane];
        h2.x = trans[(4 * c + 2) * KK + lane]; h2.y = trans[(4 * c + 3) * KK + lane];
        tcl[c] = l2; tch[c] = h2;
    }
    #pragma unroll
    for (int c = 0; c < 16; ++c) {
        asm volatile("" : "+v"(tcl[c]));
        asm volatile("" : "+v"(tch[c]));
    }

    // ------------------------------ forward ------------------------------
    float alpha0 = pb0[lane], alpha1 = pb1[lane];
    hb0[lane] = alpha0; hb1[lane] = alpha1;
    float* hp0 = hb0 + KK + lane;
    float* hp1 = hb1 + KK + lane;

    float pa[4] = { pb0[1*KK+lane], pb0[2*KK+lane], pb0[3*KK+lane], pb0[4*KK+lane] };
    float qa[4] = { pb1[1*KK+lane], pb1[2*KK+lane], pb1[3*KK+lane], pb1[4*KK+lane] };
    const float* lp0 = pb0 + 5 * KK + lane;
    const float* lp1 = pb1 + 5 * KK + lane;

    int t = 1;
    #pragma unroll 1
    for (int c = 0; c < 126; ++c) {          // t = 1..504
        #pragma unroll
        for (int u = 0; u < 4; ++u) {
            FSTEP2(pa[u], qa[u], t < seqlen0, t < seqlen1);
            pa[u] = *lp0; lp0 += KK;
            qa[u] = *lp1; lp1 += KK;
            ++t;
        }
    }
    {
        float e0 = pb0[509*KK+lane], e1 = pb0[510*KK+lane], e2 = pb0[511*KK+lane];
        float f0 = pb1[509*KK+lane], f1 = pb1[510*KK+lane], f2 = pb1[511*KK+lane];
        FSTEP2(pa[0], qa[0], 505 < seqlen0, 505 < seqlen1);
        FSTEP2(pa[1], qa[1], 506 < seqlen0, 506 < seqlen1);
        FSTEP2(pa[2], qa[2], 507 < seqlen0, 507 < seqlen1);
        FSTEP2(pa[3], qa[3], 508 < seqlen0, 508 < seqlen1);
        FSTEP2(e0, f0, 509 < seqlen0, 509 < seqlen1);
        FSTEP2(e1, f1, 510 < seqlen0, 510 < seqlen1);
        FSTEP2(e2, f2, 511 < seqlen0, 511 < seqlen1);
    }

    asm volatile("s_waitcnt vmcnt(0)" ::: "memory");   // alpha history visible

    // ---- final argmax per batch (first occurrence on ties) ----
    int cur0, cur1;
    {
        float v = alpha0; int idx = lane;
        #pragma unroll
        for (int off = 1; off < 64; off <<= 1) {
            float vo = __shfl_xor(v, off, 64);
            int io = __shfl_xor(idx, off, 64);
            bool take = (vo > v) || (vo == v && io < idx);
            v = take ? vo : v; idx = take ? io : idx;
        }
        cur0 = idx;
    }
    {
        float v = alpha1; int idx = lane;
        #pragma unroll
        for (int off = 1; off < 64; off <<= 1) {
            float vo = __shfl_xor(v, off, 64);
            int io = __shfl_xor(idx, off, 64);
            bool take = (vo > v) || (vo == v && io < idx);
            v = take ? vo : v; idx = take ? io : idx;
        }
        cur1 = idx;
    }
    int slot0 = cur0, slot1 = cur1;   // lane 63 slot = tag at t=511

    // ---- backtrace: two interleaved recompute+DPP+ballot chains ----
    float ra[8], rb[8];
    #pragma unroll
    for (int k = 0; k < 8; ++k) {
        ra[k] = hb0[(510 - k) * KK + lane];
        rb[k] = hb1[(510 - k) * KK + lane];
    }

    auto bt2 = [&](int tt, float arow, float brow) {
        unsigned u0 = 0, u1 = 0;
        bool d0 = (tt < seqlen0), d1 = (tt < seqlen1);
        if (d0) {
            float cand = arow + tT[cur0][lane];
            unsigned u = __float_as_uint(cand);
            u0 = u ^ ((unsigned)(((int)u) >> 31) | 0x80000000u);
        }
        if (d1) {
            float cand = brow + tT[cur1][lane];
            unsigned u = __float_as_uint(cand);
            u1 = u ^ ((unsigned)(((int)u) >> 31) | 0x80000000u);
        }
        if (d0) {
            unsigned run = wave_umax63(u0);
            unsigned Umax = (unsigned)__builtin_amdgcn_readlane((int)run, 63);
            unsigned long long mk = __ballot(u0 == Umax);
            cur0 = (int)__builtin_ctzll(mk);
        }
        if (d1) {
            unsigned run = wave_umax63(u1);
            unsigned Umax = (unsigned)__builtin_amdgcn_readlane((int)run, 63);
            unsigned long long mk = __ballot(u1 == Umax);
            cur1 = (int)__builtin_ctzll(mk);
        }
        const int tm = tt - 1;
        slot0 = ((tm & 63) == lane) ? cur0 : slot0;
        slot1 = ((tm & 63) == lane) ? cur1 : slot1;
        if ((tm & 63) == 0) { ob0[tm + lane] = slot0; ob1[tm + lane] = slot1; }
    };

    int T0 = 511;
    for (int c = 0; c < 63; ++c) {
        #pragma unroll
        for (int k = 0; k < 8; ++k) {
            bt2(T0 - k, ra[k], rb[k]);
            int pi = T0 - 9 - k; pi = pi < 0 ? 0 : pi;
            ra[k] = hb0[pi * KK + lane];
            rb[k] = hb1[pi * KK + lane];
        }
        T0 -= 8;
    }
    #pragma unroll
    for (int k = 0; k < 7; ++k) bt2(7 - k, ra[k], rb[k]);
}

// ---------------------------------------------------------------------------
// Fallback path (proven R1 kernels) -- only if ws can't hold alpha history.
// ---------------------------------------------------------------------------
__global__ __launch_bounds__(256) void seqlen_kernel(const float* __restrict__ inp,
                                                     int* __restrict__ seq_lens) {
    int b = blockIdx.x;
    int tid = threadIdx.x;
    const float4* p4 = (const float4*)(inp + (size_t)b * TT * KK);
    const int n4 = TT * KK / 4;
    int cnt = 0;
    for (int idx = tid; idx < n4; idx += 256) {
        float4 v = p4[idx];
        cnt += (v.x != 0.0f) + (v.y != 0.0f) + (v.z != 0.0f) + (v.w != 0.0f);
    }
    #pragma unroll
    for (int off = 32; off > 0; off >>= 1) cnt += __shfl_down(cnt, off, 64);
    __shared__ int wsum[4];
    if ((tid & 63) == 0) wsum[tid >> 6] = cnt;
    __syncthreads();
    if (tid == 0) seq_lens[b] = (wsum[0] + wsum[1] + wsum[2] + wsum[3]) >> 6;
}

__global__ __launch_bounds__(64) void viterbi_fallback(const float* __restrict__ pot,
                                                       const float* __restrict__ trans,
                                                       const int* __restrict__ seq_lens,
                                                       int* __restrict__ out) {
    __shared__ unsigned char bp[TT][KK];
    const int b = blockIdx.x;
    const int j = threadIdx.x;

    float tc[KK];
    #pragma unroll
    for (int i = 0; i < KK; ++i) tc[i] = trans[i * KK + j];

    const float* pb = pot + (size_t)b * TT * KK;
    float alpha = pb[j];
    const int seqlen = seq_lens[b];

    for (int t = 1; t < TT; ++t) {
        float ptj = pb[t * KK + j];
        float m[4]; int am[4];
        #pragma unroll
        for (int c = 0; c < 4; ++c) {
            const int i = c * 16;
            float ai = frl(alpha, i);
            m[c] = ai + tc[i];
            am[c] = i;
        }
        #pragma unroll
        for (int q = 1; q < 16; ++q) {
            #pragma unroll
            for (int c = 0; c < 4; ++c) {
                const int i = c * 16 + q;
                float ai = frl(alpha, i);
                float s = ai + tc[i];
                bool g = s > m[c];
                m[c] = g ? s : m[c];
                am[c] = g ? i : am[c];
            }
        }
        float M = m[0]; int BI = am[0];
        #pragma unroll
        for (int c = 1; c < 4; ++c) {
            bool g = m[c] > M;
            M = g ? m[c] : M;
            BI = g ? am[c] : BI;
        }
        const bool valid = (t < seqlen);
        alpha = valid ? (ptj + M) : alpha;
        bp[t][j] = (unsigned char)(valid ? BI : j);
    }

    float v = alpha; int idx = j;
    #pragma unroll
    for (int off = 1; off < 64; off <<= 1) {
        float vo = __shfl_xor(v, off, 64);
        int io = __shfl_xor(idx, off, 64);
        bool take = (vo > v) || (vo == v && io < idx);
        v = take ? vo : v;
        idx = take ? io : idx;
    }
    __syncthreads();
    if (j == 0) {
        int* ob = out + b * TT;
        int cur = idx;
        ob[TT - 1] = cur;
        for (int p = TT - 2; p >= 0; --p) {
            cur = bp[p + 1][cur];
            ob[p] = cur;
        }
    }
}

extern "C" void kernel_launch(void* const* d_in, const int* in_sizes, int n_in,
                              void* d_out, int out_size, void* d_ws, size_t ws_size,
                              hipStream_t stream) {
    const float* inp = (const float*)d_in[0];     // [B, T, K] fp32
    const float* trans = (const float*)d_in[1];   // [K, K] fp32
    int* out = (int*)d_out;                       // [B, T] int32

    const size_t histBytes = (size_t)BB * TT * KK * sizeof(float);  // 64 MB
    if (ws_size >= histBytes) {
        float* alphaH = (float*)d_ws;
        crf_fused2<<<BB / 2, 64, 0, stream>>>(inp, trans, alphaH, out);
    } else {
        int* seq = (int*)d_ws;
        seqlen_kernel<<<BB, 256, 0, stream>>>(inp, seq);
        viterbi_fallback<<<BB, KK, 0, stream>>>(inp, trans, seq, out);
    }
}

// Round 10
// 370.638 us; speedup vs baseline: 1.4195x; 1.4195x over previous
//
#include <hip/hip_runtime.h>

#define BB 512
#define TT 512
#define KK 64

typedef float v2f __attribute__((ext_vector_type(2)));

__device__ __forceinline__ float frl(float v, int lane) {
    return __int_as_float(__builtin_amdgcn_readlane(__float_as_int(v), lane));
}
__device__ __forceinline__ v2f vmax2(v2f a, v2f b) {
    v2f r; r.x = fmaxf(a.x, b.x); r.y = fmaxf(a.y, b.y); return r;
}
// wave-wide unsigned max; result valid in lane 63 (proven R4-R7)
__device__ __forceinline__ unsigned wave_umax63(unsigned x) {
    unsigned d;
    d = (unsigned)__builtin_amdgcn_update_dpp((int)x, (int)x, 0x111, 0xF, 0xF, false); x = x > d ? x : d;
    d = (unsigned)__builtin_amdgcn_update_dpp((int)x, (int)x, 0x112, 0xF, 0xF, false); x = x > d ? x : d;
    d = (unsigned)__builtin_amdgcn_update_dpp((int)x, (int)x, 0x114, 0xF, 0xF, false); x = x > d ? x : d;
    d = (unsigned)__builtin_amdgcn_update_dpp((int)x, (int)x, 0x118, 0xF, 0xF, false); x = x > d ? x : d;
    d = (unsigned)__builtin_amdgcn_update_dpp((int)x, (int)x, 0x142, 0xA, 0xF, false); x = x > d ? x : d;
    d = (unsigned)__builtin_amdgcn_update_dpp((int)x, (int)x, 0x143, 0xC, 0xF, false); x = x > d ? x : d;
    return x;
}

__device__ __forceinline__ void gl_lds16(const float* g, float* l) {
    // 16B/lane async global->LDS; LDS dest = uniform base + lane*16 (proven R3)
    __builtin_amdgcn_global_load_lds((const __attribute__((address_space(1))) void*)g,
                                     (__attribute__((address_space(3))) void*)l, 16, 0, 0);
}

// One Viterbi step via LDS broadcast (R7). PT comes from the LDS stage ring.
#define FSTEP(PT, TC) do {                                                      \
    la[lane] = alpha;                                                           \
    asm volatile("" ::: "memory");                                              \
    v2f acc0, acc1, acc2, acc3;                                                 \
    {                                                                           \
        float4 a4 = ((float4*)la)[0];                                           \
        v2f lo; lo.x = a4.x; lo.y = a4.y; acc0 = lo + tcl[0];                   \
        v2f hi; hi.x = a4.z; hi.y = a4.w; acc1 = hi + tch[0];                   \
        a4 = ((float4*)la)[1];                                                  \
        lo.x = a4.x; lo.y = a4.y; acc2 = lo + tcl[1];                           \
        hi.x = a4.z; hi.y = a4.w; acc3 = hi + tch[1];                           \
    }                                                                           \
    _Pragma("unroll")                                                           \
    for (int c = 2; c < 16; c += 2) {                                           \
        float4 a4 = ((float4*)la)[c];                                           \
        v2f lo; lo.x = a4.x; lo.y = a4.y; acc0 = vmax2(acc0, lo + tcl[c]);      \
        v2f hi; hi.x = a4.z; hi.y = a4.w; acc1 = vmax2(acc1, hi + tch[c]);      \
        a4 = ((float4*)la)[c + 1];                                              \
        lo.x = a4.x; lo.y = a4.y; acc2 = vmax2(acc2, lo + tcl[c + 1]);          \
        hi.x = a4.z; hi.y = a4.w; acc3 = vmax2(acc3, hi + tch[c + 1]);          \
    }                                                                           \
    v2f mm = vmax2(vmax2(acc0, acc1), vmax2(acc2, acc3));                       \
    float M = fmaxf(mm.x, mm.y);                                                \
    alpha = (TC) ? (PT + M) : alpha;                                            \
    *hp = alpha; hp += KK;                                                      \
} while (0)

// ---------------------------------------------------------------------------
// Fused: count -> max-only forward (pot from LDS stage, alpha history to ws)
// -> DPP/ballot backtrace. One wave per batch, 1 dispatch.
//
// Staging schedule (race-proof, fixes R9):
//   chunk n = rows [32n, 32n+32) -> stage[n&1].
//   last READ of chunk n data: ring refill rn=32n+31 at group c=8n+6, u=2.
//   ISSUE chunk n+2 at group start c=8n+7        (buffer dead: strictly after)
//   WAIT  vmcnt(0)  at group start c=8n+14       (first read of chunk n+2 is
//                                                 refill rn=32n+64 at c=8n+14, u=3)
// ---------------------------------------------------------------------------
__global__ __launch_bounds__(64, 1) void crf_fused(const float* __restrict__ pot,
                                                   const float* __restrict__ trans,
                                                   float* __restrict__ alphaH,
                                                   int* __restrict__ out) {
    __shared__ float tT[KK][KK + 1];     // tT[j][i] = trans[i][j] (backtrace)
    __shared__ float la[KK];             // alpha broadcast buffer
    __shared__ float stage[2][32 * KK];  // 16 KB pot staging, 32 steps/chunk

    const int b = blockIdx.x;
    const int lane = threadIdx.x;
    const float* pb = pot + (size_t)b * TT * KK;
    float* hb = alphaH + (size_t)b * TT * KK;
    int* ob = out + b * TT;

    // issue staging of chunks 0,1 first (latency hidden under count phase)
    #pragma unroll
    for (int k = 0; k < 8; ++k) gl_lds16(pb + k * 256 + lane * 4, &stage[0][k * 256]);
    #pragma unroll
    for (int k = 0; k < 8; ++k) gl_lds16(pb + 2048 + k * 256 + lane * 4, &stage[1][k * 256]);

    // ---- seq_len: count this batch's nonzeros (warms L2/L3 for pot) ----
    int cnt = 0;
    {
        const float4* p4 = (const float4*)pb;
        #pragma unroll 4
        for (int r = 0; r < 128; ++r) {
            float4 v = p4[lane + 64 * r];
            cnt += (v.x != 0.f) + (v.y != 0.f) + (v.z != 0.f) + (v.w != 0.f);
        }
        #pragma unroll
        for (int off = 32; off > 0; off >>= 1) cnt += __shfl_xor(cnt, off, 64);
    }
    const int seqlen = cnt >> 6;   // trunc(mean) — fp32-exact per R1

    // ---- stage transposed trans for backtrace (same wave: no barrier) ----
    #pragma unroll 8
    for (int r = 0; r < KK; ++r) tT[lane][r] = trans[r * KK + lane];

    // ---- trans column 'lane' as v2f pairs; pin vs remat (proven R6) ----
    v2f tcl[16], tch[16];   // tcl[c] = rows 4c,4c+1; tch[c] = rows 4c+2,4c+3
    #pragma unroll
    for (int c = 0; c < 16; ++c) {
        v2f l2, h2;
        l2.x = trans[(4 * c + 0) * KK + lane]; l2.y = trans[(4 * c + 1) * KK + lane];
        h2.x = trans[(4 * c + 2) * KK + lane]; h2.y = trans[(4 * c + 3) * KK + lane];
        tcl[c] = l2; tch[c] = h2;
    }
    #pragma unroll
    for (int c = 0; c < 16; ++c) {
        asm volatile("" : "+v"(tcl[c]));
        asm volatile("" : "+v"(tch[c]));
    }

    asm volatile("s_waitcnt vmcnt(0)" ::: "memory");  // chunks 0,1 resident

    // ------------------------------ forward ------------------------------
    float alpha = stage[0][lane];   // row 0
    hb[lane] = alpha;
    float* hp = hb + KK + lane;

    // 4-deep ring of potentials, fed from the LDS stage (rows t+4)
    float pf[4] = { stage[0][1 * KK + lane], stage[0][2 * KK + lane],
                    stage[0][3 * KK + lane], stage[0][4 * KK + lane] };

    int t = 1;
    #pragma unroll 1
    for (int c = 0; c < 126; ++c) {          // t = 1..504
        if ((c & 7) == 6) {
            // drain the DMA issued 7 groups ago (next chunk's first read is
            // the ring refill at THIS group's u=3)
            asm volatile("s_waitcnt vmcnt(0)" ::: "memory");
        } else if ((c & 7) == 7) {
            // buffer provably dead (last read of chunk cn-2 was group c-1,u=2)
            const int cn = ((1 + 4 * c) >> 5) + 2;
            if (cn < 16) {
                const float* g0 = pb + cn * 32 * KK;
                float* l0 = &stage[cn & 1][0];
                #pragma unroll
                for (int k = 0; k < 8; ++k) gl_lds16(g0 + k * 256 + lane * 4, l0 + k * 256);
            }
        }
        #pragma unroll
        for (int u = 0; u < 4; ++u) {
            FSTEP(pf[u], t < seqlen);
            int rn = t + 4; rn = rn > 511 ? 511 : rn;     // clamped ring refill
            pf[u] = stage[(rn >> 5) & 1][(rn & 31) * KK + lane];
            ++t;
        }
    }
    // tail: t = 505..511 (pf holds rows 505..508; 509..511 from stage ring)
    FSTEP(pf[0], 505 < seqlen);
    FSTEP(pf[1], 506 < seqlen);
    FSTEP(pf[2], 507 < seqlen);
    FSTEP(pf[3], 508 < seqlen);
    {
        float e0 = stage[1][(509 & 31) * KK + lane];
        float e1 = stage[1][(510 & 31) * KK + lane];
        float e2 = stage[1][(511 & 31) * KK + lane];
        FSTEP(e0, 509 < seqlen);
        FSTEP(e1, 510 < seqlen);
        FSTEP(e2, 511 < seqlen);
    }

    asm volatile("s_waitcnt vmcnt(0)" ::: "memory");   // alpha history visible

    // ---- final argmax over live alpha (first occurrence on ties) ----
    float v = alpha; int idx = lane;
    #pragma unroll
    for (int off = 1; off < 64; off <<= 1) {
        float vo = __shfl_xor(v, off, 64);
        int io = __shfl_xor(idx, off, 64);
        bool take = (vo > v) || (vo == v && io < idx);
        v = take ? vo : v;
        idx = take ? io : idx;
    }
    int cur = idx;          // uniform
    int slot = cur;         // lane 63 slot survives as tag at t=511

    // ---- backtrace: recompute + DPP-max + ballot first-match (proven) ----
    float r0 = hb[510 * KK + lane], r1 = hb[509 * KK + lane], r2 = hb[508 * KK + lane],
          r3 = hb[507 * KK + lane], r4 = hb[506 * KK + lane], r5 = hb[505 * KK + lane],
          r6 = hb[504 * KK + lane], r7 = hb[503 * KK + lane];

    auto bt_step = [&](int tt, float arow) {
        if (tt < seqlen) {   // uniform
            float cand = arow + tT[cur][lane];
            unsigned u = __float_as_uint(cand);
            u = u ^ ((unsigned)(((int)u) >> 31) | 0x80000000u);   // sortable key
            unsigned run = wave_umax63(u);
            unsigned Umax = (unsigned)__builtin_amdgcn_readlane((int)run, 63);
            unsigned long long mk = __ballot(u == Umax);
            cur = (int)__builtin_ctzll(mk);                        // first i == argmax
        }
        const int tm = tt - 1;
        slot = ((tm & 63) == lane) ? cur : slot;
        if ((tm & 63) == 0) ob[tm + lane] = slot;
    };

    int T0 = 511;
    for (int c = 0; c < 63; ++c) {
        bt_step(T0 - 0, r0); { int pi = T0 - 9;  pi = pi < 0 ? 0 : pi; r0 = hb[pi * KK + lane]; }
        bt_step(T0 - 1, r1); { int pi = T0 - 10; pi = pi < 0 ? 0 : pi; r1 = hb[pi * KK + lane]; }
        bt_step(T0 - 2, r2); { int pi = T0 - 11; pi = pi < 0 ? 0 : pi; r2 = hb[pi * KK + lane]; }
        bt_step(T0 - 3, r3); { int pi = T0 - 12; pi = pi < 0 ? 0 : pi; r3 = hb[pi * KK + lane]; }
        bt_step(T0 - 4, r4); { int pi = T0 - 13; pi = pi < 0 ? 0 : pi; r4 = hb[pi * KK + lane]; }
        bt_step(T0 - 5, r5); { int pi = T0 - 14; pi = pi < 0 ? 0 : pi; r5 = hb[pi * KK + lane]; }
        bt_step(T0 - 6, r6); { int pi = T0 - 15; pi = pi < 0 ? 0 : pi; r6 = hb[pi * KK + lane]; }
        bt_step(T0 - 7, r7); { int pi = T0 - 16; pi = pi < 0 ? 0 : pi; r7 = hb[pi * KK + lane]; }
        T0 -= 8;
    }
    bt_step(7, r0); bt_step(6, r1); bt_step(5, r2); bt_step(4, r3);
    bt_step(3, r4); bt_step(2, r5); bt_step(1, r6);
}

// ---------------------------------------------------------------------------
// Fallback path (proven R1 kernels) -- only if ws can't hold alpha history.
// ---------------------------------------------------------------------------
__global__ __launch_bounds__(256) void seqlen_kernel(const float* __restrict__ inp,
                                                     int* __restrict__ seq_lens) {
    int b = blockIdx.x;
    int tid = threadIdx.x;
    const float4* p4 = (const float4*)(inp + (size_t)b * TT * KK);
    const int n4 = TT * KK / 4;
    int cnt = 0;
    for (int idx = tid; idx < n4; idx += 256) {
        float4 v = p4[idx];
        cnt += (v.x != 0.0f) + (v.y != 0.0f) + (v.z != 0.0f) + (v.w != 0.0f);
    }
    #pragma unroll
    for (int off = 32; off > 0; off >>= 1) cnt += __shfl_down(cnt, off, 64);
    __shared__ int wsum[4];
    if ((tid & 63) == 0) wsum[tid >> 6] = cnt;
    __syncthreads();
    if (tid == 0) seq_lens[b] = (wsum[0] + wsum[1] + wsum[2] + wsum[3]) >> 6;
}

__global__ __launch_bounds__(64) void viterbi_fallback(const float* __restrict__ pot,
                                                       const float* __restrict__ trans,
                                                       const int* __restrict__ seq_lens,
                                                       int* __restrict__ out) {
    __shared__ unsigned char bp[TT][KK];
    const int b = blockIdx.x;
    const int j = threadIdx.x;

    float tc[KK];
    #pragma unroll
    for (int i = 0; i < KK; ++i) tc[i] = trans[i * KK + j];

    const float* pb = pot + (size_t)b * TT * KK;
    float alpha = pb[j];
    const int seqlen = seq_lens[b];

    for (int t = 1; t < TT; ++t) {
        float ptj = pb[t * KK + j];
        float m[4]; int am[4];
        #pragma unroll
        for (int c = 0; c < 4; ++c) {
            const int i = c * 16;
            float ai = frl(alpha, i);
            m[c] = ai + tc[i];
            am[c] = i;
        }
        #pragma unroll
        for (int q = 1; q < 16; ++q) {
            #pragma unroll
            for (int c = 0; c < 4; ++c) {
                const int i = c * 16 + q;
                float ai = frl(alpha, i);
                float s = ai + tc[i];
                bool g = s > m[c];
                m[c] = g ? s : m[c];
                am[c] = g ? i : am[c];
            }
        }
        float M = m[0]; int BI = am[0];
        #pragma unroll
        for (int c = 1; c < 4; ++c) {
            bool g = m[c] > M;
            M = g ? m[c] : M;
            BI = g ? am[c] : BI;
        }
        const bool valid = (t < seqlen);
        alpha = valid ? (ptj + M) : alpha;
        bp[t][j] = (unsigned char)(valid ? BI : j);
    }

    float v = alpha; int idx = j;
    #pragma unroll
    for (int off = 1; off < 64; off <<= 1) {
        float vo = __shfl_xor(v, off, 64);
        int io = __shfl_xor(idx, off, 64);
        bool take = (vo > v) || (vo == v && io < idx);
        v = take ? vo : v;
        idx = take ? io : idx;
    }
    __syncthreads();
    if (j == 0) {
        int* ob = out + b * TT;
        int cur = idx;
        ob[TT - 1] = cur;
        for (int p = TT - 2; p >= 0; --p) {
            cur = bp[p + 1][cur];
            ob[p] = cur;
        }
    }
}

extern "C" void kernel_launch(void* const* d_in, const int* in_sizes, int n_in,
                              void* d_out, int out_size, void* d_ws, size_t ws_size,
                              hipStream_t stream) {
    const float* inp = (const float*)d_in[0];     // [B, T, K] fp32
    const float* trans = (const float*)d_in[1];   // [K, K] fp32
    int* out = (int*)d_out;                       // [B, T] int32

    const size_t histBytes = (size_t)BB * TT * KK * sizeof(float);  // 64 MB
    if (ws_size >= histBytes) {
        float* alphaH = (float*)d_ws;
        crf_fused<<<BB, 64, 0, stream>>>(inp, trans, alphaH, out);
    } else {
        int* seq = (int*)d_ws;
        seqlen_kernel<<<BB, 256, 0, stream>>>(inp, seq);
        viterbi_fallback<<<BB, KK, 0, stream>>>(inp, trans, seq, out);
    }
}